// Round 4
// baseline (1883.435 us; speedup 1.0000x reference)
//
#include <hip/hip_runtime.h>
#include <stdint.h>

typedef __attribute__((ext_vector_type(4))) float f32x4;
typedef __attribute__((ext_vector_type(8))) __bf16 bf16x8;

__device__ __forceinline__ ushort f2bf(float f) {
  union { float f; uint32_t u; } v; v.f = f;
  uint32_t r = v.u + 0x7fffu + ((v.u >> 16) & 1u);
  return (ushort)(r >> 16);
}
__device__ __forceinline__ float bf2f(uint32_t h) {
  union { uint32_t u; float f; } v; v.u = h << 16;
  return v.f;
}

// async global->LDS, 16B/lane; LDS dest is wave-uniform base + lane*16 (linear).
__device__ __forceinline__ void gload16(const void* g, const void* l) {
  __builtin_amdgcn_global_load_lds(
      (const __attribute__((address_space(1))) void*)(uintptr_t)g,
      (__attribute__((address_space(3))) void*)(uint32_t)(uintptr_t)l,
      16, 0, 0);
}

// ---------------------------------------------------------------------------
// GEMM: C(M,N) = A(M,K) * B^T(N,K), batched over blockIdx.z.
// 128x128 tile, BK=32, 256 threads (4 waves 2x2), ring-3 LDS (48KB -> 3
// blocks/CU), counted vmcnt (loads in flight across barriers), K-chunk-major
// LDS layout (conflict-free ds_read_b128, verified round 3).
//   slot (16KB): A-plane [4 kchunk][128 row][16B], B-plane same at +8KB.
// EPI 0: out bf16 = relu(acc + bias[n]); out += oStride*bz  (batched experts)
// EPI 1: expert-2 split-K: bz = e*2+kc; atomicAdd(z, gates*(acc + kc?0:bias))
// EPI 3: fused LoRA: cols < ldo -> out+bias, else out+oStride+bias2
// ---------------------------------------------------------------------------
#define SLOT 16384

template<int EPI>
__global__ __launch_bounds__(256, 3)
void gemm128(const ushort* __restrict__ A, const ushort* __restrict__ Bt,
             const float* __restrict__ bias, const float* __restrict__ bias2,
             void* __restrict__ outp,
             int K, int lda, int ldb, int ldo,
             size_t aStride, size_t bStride, int biasStride, size_t oStride,
             const float* __restrict__ gates, int ebase, int kChunk)
{
  __shared__ __attribute__((aligned(16))) char smem[3 * SLOT]; // 48 KB

  const int t    = threadIdx.x;
  const int lane = t & 63;
  const int wid  = t >> 6;
  const int wr   = wid >> 1, wc = wid & 1;    // 2x2 waves; wave C = 64x64
  const int fr   = lane & 15, fq = lane >> 4;
  const int bx   = blockIdx.x, by = blockIdx.y, bz = blockIdx.z;

  const int eb = (EPI == 1) ? (bz >> 1) : bz;     // expert index within batch
  const int kc = (EPI == 1) ? (bz & 1)  : 0;      // K-split chunk

  // staging source (pre-permuted for K-chunk-major LDS; dest linear)
  const int R  = t & 127;      // tile row staged by this thread
  const int jA = t >> 7;       // k-chunk 0/1 (first call; +2 for second)
  const ushort* a0 = A + aStride * eb + (size_t)kc * kChunk
                       + (size_t)(by * 128 + R) * lda + jA * 8;
  const ushort* a1 = a0 + 16;
  const ushort* b0 = Bt + bStride * eb + (size_t)kc * kChunk
                       + (size_t)(bx * 128 + R) * ldb + jA * 8;
  const ushort* b1 = b0 + 16;
  const int dA0 = t * 16,        dA1 = 4096 + t * 16;
  const int dB0 = 8192 + t * 16, dB1 = 12288 + t * 16;

  // ds_read offsets within slot: row = wr*64 + m*16 + fr, kchunk = fq
  const int aOff = fq * 2048 + (wr * 64 + fr) * 16;           // + m*256
  const int bOff = 8192 + fq * 2048 + (wc * 64 + fr) * 16;    // + n*256

  f32x4 acc[4][4];
#pragma unroll
  for (int m = 0; m < 4; ++m)
#pragma unroll
    for (int n = 0; n < 4; ++n) acc[m][n] = (f32x4){0.f, 0.f, 0.f, 0.f};

  const int NT = K >> 5;
  int sc = 0, ss = 2;

  auto STAGE = [&](int slot) {
    char* d = smem + slot * SLOT;
    gload16(a0, d + dA0); gload16(a1, d + dA1);
    gload16(b0, d + dB0); gload16(b1, d + dB1);
    a0 += 32; a1 += 32; b0 += 32; b1 += 32;
  };

  STAGE(0); STAGE(1);          // 8 loads in flight

  for (int tt = 0; tt < NT; ++tt) {
    if (tt < NT - 2) {
      STAGE(ss); if (++ss == 3) ss = 0;
      asm volatile("s_waitcnt vmcnt(8)" ::: "memory");   // tile tt landed
    } else if (tt == NT - 2) {
      asm volatile("s_waitcnt vmcnt(4)" ::: "memory");
    } else {
      asm volatile("s_waitcnt vmcnt(0)" ::: "memory");
    }
    asm volatile("s_barrier" ::: "memory");

    const char* base = smem + sc * SLOT;
    bf16x8 af[4], bf[4];
#pragma unroll
    for (int m = 0; m < 4; ++m) af[m] = *(const bf16x8*)(base + aOff + m * 256);
#pragma unroll
    for (int n = 0; n < 4; ++n) bf[n] = *(const bf16x8*)(base + bOff + n * 256);

    __builtin_amdgcn_s_setprio(1);
#pragma unroll
    for (int m = 0; m < 4; ++m)
#pragma unroll
      for (int n = 0; n < 4; ++n)
        acc[m][n] = __builtin_amdgcn_mfma_f32_16x16x32_bf16(af[m], bf[n], acc[m][n], 0, 0, 0);
    __builtin_amdgcn_s_setprio(0);

    asm volatile("s_barrier" ::: "memory");
    if (++sc == 3) sc = 0;
  }

  // epilogue: col = gcol0 + n*16, row = grow0 + m*16 + j   [m89 mapping]
  const int grow0 = by * 128 + wr * 64 + fq * 4;
  const int gcol0 = bx * 128 + wc * 64 + fr;

  if (EPI == 0) {
    ushort* o = (ushort*)outp + oStride * eb;
    const float* bb = bias + (size_t)biasStride * eb;
#pragma unroll
    for (int n = 0; n < 4; ++n) {
      const int c = gcol0 + n * 16;
      const float bv = bb[c];
#pragma unroll
      for (int m = 0; m < 4; ++m)
#pragma unroll
        for (int j = 0; j < 4; ++j) {
          const int r = grow0 + m * 16 + j;
          const float v = acc[m][n][j] + bv;
          o[(size_t)r * ldo + c] = f2bf(v > 0.f ? v : 0.f);
        }
    }
  } else if (EPI == 1) {
    float* o = (float*)outp;
    const float* bb = bias + (size_t)biasStride * eb;
    const int e = ebase + eb;
    const float bscale = (kc == 0) ? 1.f : 0.f;
#pragma unroll
    for (int n = 0; n < 4; ++n) {
      const int c = gcol0 + n * 16;
      const float bv = bb[c] * bscale;
#pragma unroll
      for (int m = 0; m < 4; ++m)
#pragma unroll
        for (int j = 0; j < 4; ++j) {
          const int r = grow0 + m * 16 + j;
          atomicAdd(&o[(size_t)r * ldo + c],
                    gates[(size_t)r * 16 + e] * (acc[m][n][j] + bv));
        }
    }
  } else { // EPI 3: fused LoRA heads
    const bool second = (gcol0 >= ldo);
    const float* bp = second ? bias2 : bias;
    float* o = (float*)outp + (second ? oStride : 0);
#pragma unroll
    for (int n = 0; n < 4; ++n) {
      const int cc = gcol0 + n * 16 - (second ? ldo : 0);
      const float bv = bp[cc];
#pragma unroll
      for (int m = 0; m < 4; ++m)
#pragma unroll
        for (int j = 0; j < 4; ++j) {
          const int r = grow0 + m * 16 + j;
          o[(size_t)r * ldo + cc] = acc[m][n][j] + bv;
        }
    }
  }
}

// ---------------------------------------------------------------------------
// transpose + cvt: in (K,N) f32 -> out (N,K) bf16. 64x64 tiles, vectorized.
// ---------------------------------------------------------------------------
__global__ __launch_bounds__(256)
void transpose_cvt(const float* __restrict__ in, ushort* __restrict__ out,
                   int K, int N, size_t inStride, size_t outStride)
{
  __shared__ float tile[64][65];
  const float* I = in + inStride * blockIdx.z;
  ushort* O = out + outStride * blockIdx.z;
  const int n0 = blockIdx.x * 64, k0 = blockIdx.y * 64;
  const int t = threadIdx.x;
  const int r = t >> 4, cv = (t & 15) * 4;
#pragma unroll
  for (int p = 0; p < 4; ++p) {
    const int kr = r + p * 16;
    const float4 v = *(const float4*)&I[(size_t)(k0 + kr) * N + (n0 + cv)];
    tile[kr][cv] = v.x; tile[kr][cv + 1] = v.y; tile[kr][cv + 2] = v.z; tile[kr][cv + 3] = v.w;
  }
  __syncthreads();
#pragma unroll
  for (int p = 0; p < 4; ++p) {
    const int nr = r + p * 16;
    ushort4 o4;
    o4.x = f2bf(tile[cv + 0][nr]); o4.y = f2bf(tile[cv + 1][nr]);
    o4.z = f2bf(tile[cv + 2][nr]); o4.w = f2bf(tile[cv + 3][nr]);
    *(ushort4*)&O[(size_t)(n0 + nr) * K + (k0 + cv)] = o4;
  }
}

// x = concat(s, c) as bf16, row stride 1536. 8 elems/thread.
__global__ __launch_bounds__(256)
void build_x(const float* __restrict__ s, const float* __restrict__ c, ushort* __restrict__ x)
{
  const size_t i = (size_t)blockIdx.x * 256 + threadIdx.x;
  const size_t b = i / 192;
  const int col  = (int)(i % 192) * 8;
  const float* src = (col < 1024) ? (s + b * 1024 + col) : (c + b * 512 + (col - 1024));
  const float4 v0 = ((const float4*)src)[0];
  const float4 v1 = ((const float4*)src)[1];
  uint4 o;
  o.x = f2bf(v0.x) | ((uint32_t)f2bf(v0.y) << 16);
  o.y = f2bf(v0.z) | ((uint32_t)f2bf(v0.w) << 16);
  o.z = f2bf(v1.x) | ((uint32_t)f2bf(v1.y) << 16);
  o.w = f2bf(v1.z) | ((uint32_t)f2bf(v1.w) << 16);
  *(uint4*)(x + i * 8) = o;
}

__global__ __launch_bounds__(256)
void cvt_bf16(const float* __restrict__ in, ushort* __restrict__ out)
{
  const size_t i = (size_t)blockIdx.x * 256 + threadIdx.x;
  const float4 v0 = ((const float4*)(in + i * 8))[0];
  const float4 v1 = ((const float4*)(in + i * 8))[1];
  uint4 o;
  o.x = f2bf(v0.x) | ((uint32_t)f2bf(v0.y) << 16);
  o.y = f2bf(v0.z) | ((uint32_t)f2bf(v0.w) << 16);
  o.z = f2bf(v1.x) | ((uint32_t)f2bf(v1.y) << 16);
  o.w = f2bf(v1.z) | ((uint32_t)f2bf(v1.w) << 16);
  *(uint4*)(out + i * 8) = o;
}

// gating second layer + softmax: one wave per row.
__global__ __launch_bounds__(256)
void gating2_softmax(const ushort* __restrict__ hg, const float* __restrict__ Wg2,
                     const float* __restrict__ bg2, float* __restrict__ gates)
{
  const int row  = (int)((blockIdx.x * 256 + threadIdx.x) >> 6);
  const int lane = threadIdx.x & 63;
  float acc[16];
#pragma unroll
  for (int e = 0; e < 16; ++e) acc[e] = 0.f;
  const ushort* hrow = hg + (size_t)row * 2048;
#pragma unroll
  for (int it = 0; it < 4; ++it) {
    const int kb = it * 512 + lane * 8;
    const uint4 pk = *(const uint4*)(hrow + kb);
    float hv[8] = { bf2f(pk.x & 0xffffu), bf2f(pk.x >> 16),
                    bf2f(pk.y & 0xffffu), bf2f(pk.y >> 16),
                    bf2f(pk.z & 0xffffu), bf2f(pk.z >> 16),
                    bf2f(pk.w & 0xffffu), bf2f(pk.w >> 16) };
#pragma unroll
    for (int j = 0; j < 8; ++j) {
      const float* wrow = Wg2 + (size_t)(kb + j) * 16;
#pragma unroll
      for (int e = 0; e < 16; ++e) acc[e] += hv[j] * wrow[e];
    }
  }
#pragma unroll
  for (int e = 0; e < 16; ++e) {
#pragma unroll
    for (int off = 32; off > 0; off >>= 1) acc[e] += __shfl_xor(acc[e], off);
    acc[e] += bg2[e];
  }
  float mx = acc[0];
#pragma unroll
  for (int e = 1; e < 16; ++e) mx = fmaxf(mx, acc[e]);
  float sum = 0.f;
#pragma unroll
  for (int e = 0; e < 16; ++e) { acc[e] = __expf(acc[e] - mx); sum += acc[e]; }
  const float inv = 1.f / sum;
  if (lane == 0) {
#pragma unroll
    for (int e = 0; e < 16; ++e) gates[(size_t)row * 16 + e] = acc[e] * inv;
  }
}

// ---------------------------------------------------------------------------
extern "C" void kernel_launch(void* const* d_in, const int* in_sizes, int n_in,
                              void* d_out, int out_size, void* d_ws, size_t ws_size,
                              hipStream_t stream)
{
  (void)in_sizes; (void)n_in; (void)out_size;
  const float* s   = (const float*)d_in[0];
  const float* c   = (const float*)d_in[1];
  const float* Wg1 = (const float*)d_in[2];
  const float* bg1 = (const float*)d_in[3];
  const float* Wg2 = (const float*)d_in[4];
  const float* bg2 = (const float*)d_in[5];
  const float* We1 = (const float*)d_in[6];
  const float* be1 = (const float*)d_in[7];
  const float* We2 = (const float*)d_in[8];
  const float* be2 = (const float*)d_in[9];
  const float* WA  = (const float*)d_in[10];
  const float* bA  = (const float*)d_in[11];
  const float* WB  = (const float*)d_in[12];
  const float* bB  = (const float*)d_in[13];
  float* out = (float*)d_out;

  char* ws = (char*)d_ws;
  size_t off = 0;
  auto alloc = [&](size_t bytes) {
    void* p = ws + off; off += (bytes + 255) & ~(size_t)255; return p;
  };
  ushort* x     = (ushort*)alloc((size_t)4096 * 1536 * 2);      // 12.6 MB
  ushort* We1T  = (ushort*)alloc((size_t)16 * 2048 * 1536 * 2); // 100.7 MB
  ushort* We2T  = (ushort*)alloc((size_t)16 * 512 * 2048 * 2);  // 33.6 MB
  ushort* WABT  = (ushort*)alloc((size_t)32768 * 512 * 2);      // 33.6 MB
  float*  gates = (float*)alloc((size_t)4096 * 16 * 4);
  float*  z     = (float*)alloc((size_t)4096 * 512 * 4);        //  8.4 MB
  ushort* zb    = (ushort*)alloc((size_t)4096 * 512 * 2);       //  4.2 MB

  const size_t BH = (size_t)4096 * 2048 * 2; // 16.8 MB per expert h
  size_t rem = (ws_size > off) ? ws_size - off : 0;
  int GS = 2;
  if (rem >= 8 * BH) GS = 8;
  else if (rem >= 4 * BH) GS = 4;
  ushort* h = (ushort*)alloc((size_t)GS * BH);
  // aliases inside h (dead before h is first written):
  ushort* Wg1T = h;                                             // 4.2 MB
  ushort* hg   = (ushort*)((char*)h + (size_t)2048 * 1024 * 2); // 16.8 MB

  const size_t S_We1 = (size_t)2048 * 1536;
  const size_t S_We2 = (size_t)512 * 2048;
  const size_t S_h   = (size_t)4096 * 2048;

  build_x<<<3072, 256, 0, stream>>>(s, c, x);
  transpose_cvt<<<dim3(32, 16, 1),  256, 0, stream>>>(Wg1, Wg1T, 1024, 2048, 0, 0);
  transpose_cvt<<<dim3(32, 24, 16), 256, 0, stream>>>(We1, We1T, 1536, 2048, S_We1, S_We1);
  transpose_cvt<<<dim3(8, 32, 16),  256, 0, stream>>>(We2, We2T, 2048, 512, S_We2, S_We2);
  transpose_cvt<<<dim3(256, 8, 1),  256, 0, stream>>>(WA, WABT, 512, 16384, 0, 0);
  transpose_cvt<<<dim3(256, 8, 1),  256, 0, stream>>>(WB, WABT + (size_t)16384 * 512, 512, 16384, 0, 0);

  // gating: hg = relu(s @ Wg1 + bg1), then gates = softmax(hg @ Wg2 + bg2)
  gemm128<0><<<dim3(16, 32, 1), 256, 0, stream>>>(x, Wg1T, bg1, nullptr, hg,
      1024, 1536, 1024, 2048, 0, 0, 0, 0, nullptr, 0, 0);
  gating2_softmax<<<1024, 256, 0, stream>>>(hg, Wg2, bg2, gates);

  hipMemsetAsync(z, 0, (size_t)4096 * 512 * 4, stream);

  for (int g = 0; g < 16; g += GS) {
    // h[e] = relu(x @ We1[e]^T + be1[e])
    gemm128<0><<<dim3(16, 32, GS), 256, 0, stream>>>(x, We1T + (size_t)g * S_We1,
        be1 + (size_t)g * 2048, nullptr, h,
        1536, 1536, 1536, 2048, 0, S_We1, 2048, S_h, nullptr, 0, 0);
    // z += gates[:,e] * (h[e] @ We2[e]^T + be2[e]); K split x2 (bz = e*2+kc)
    gemm128<1><<<dim3(4, 32, GS * 2), 256, 0, stream>>>(h, We2T + (size_t)g * S_We2,
        be2 + (size_t)g * 512, nullptr, z,
        1024, 2048, 2048, 512, S_h, S_We2, 512, 0, gates, g, 1024);
  }

  cvt_bf16<<<1024, 256, 0, stream>>>(z, zb);

  // fused LoRA heads: C = zb @ [WA; WB]^T, split-output epilogue
  gemm128<3><<<dim3(256, 32, 1), 256, 0, stream>>>(zb, WABT, bA, bB, out,
      512, 512, 512, 16384, 0, 0, 0, (size_t)4096 * 16384, nullptr, 0, 0);
}

// Round 5
// 1767.500 us; speedup vs baseline: 1.0656x; 1.0656x over previous
//
#include <hip/hip_runtime.h>
#include <stdint.h>

typedef __attribute__((ext_vector_type(4))) float f32x4;
typedef __attribute__((ext_vector_type(8))) __bf16 bf16x8;

__device__ __forceinline__ ushort f2bf(float f) {
  union { float f; uint32_t u; } v; v.f = f;
  uint32_t r = v.u + 0x7fffu + ((v.u >> 16) & 1u);
  return (ushort)(r >> 16);
}
__device__ __forceinline__ float bf2f(uint32_t h) {
  union { uint32_t u; float f; } v; v.u = h << 16;
  return v.f;
}

// async global->LDS, 16B/lane; LDS dest is wave-uniform base + lane*16.
__device__ __forceinline__ void gload16(const void* g, const void* l) {
  __builtin_amdgcn_global_load_lds(
      (const __attribute__((address_space(1))) void*)(uintptr_t)g,
      (__attribute__((address_space(3))) void*)(uint32_t)(uintptr_t)l,
      16, 0, 0);
}

// ---------------------------------------------------------------------------
// GEMM: C(M,N) = A(M,K) * B^T(N,K), batched over bz. Round-2 structure
// (coalesced staging, 2-barrier loop) + XCD-chunked block remap:
//   o = hw linear block id; p = (o&7)*(P/8) + (o>>3)  -> each XCD gets a
//   contiguous chunk of work (expert-1: chunk == one expert -> B fits L2).
// COL=1 decodes p column-major (LoRA: chunk's B slice = 4MB, fits L2).
// EPI 0: out bf16 = relu(acc + bias[n]); out += oStride*eb
// EPI 1: expert-2 split-K: bz = e*2+kc; atomicAdd(z, gates*(acc + kc?0:bias))
// EPI 3: fused LoRA: cols < ldo -> out+bias, else out+oStride+bias2
// ---------------------------------------------------------------------------
template<int EPI, int COL>
__global__ __launch_bounds__(256)
void gemm_bt(const ushort* __restrict__ A, const ushort* __restrict__ Bt,
             const float* __restrict__ bias, const float* __restrict__ bias2,
             void* __restrict__ outp,
             int K, int lda, int ldb, int ldo,
             size_t aStride, size_t bStride, int biasStride, size_t oStride,
             const float* __restrict__ gates, int ebase, int kChunk)
{
  __shared__ __attribute__((aligned(16))) ushort As[128 * 32];
  __shared__ __attribute__((aligned(16))) ushort Bs[128 * 32];

  // --- XCD-chunked remap (bijective; all grids have P%8==0) ---
  const int gx = gridDim.x, gy = gridDim.y;
  const int P  = gx * gy * gridDim.z;
  const int o  = blockIdx.x + gx * (blockIdx.y + gy * blockIdx.z);
  const int p  = (o & 7) * (P >> 3) + (o >> 3);
  int bx, by, bz;
  if (COL) { by = p % gy; const int q = p / gy; bx = q % gx; bz = q / gx; }
  else     { bx = p % gx; const int q = p / gx; by = q % gy; bz = q / gy; }

  const int eb = (EPI == 1) ? (bz >> 1) : bz;   // expert index within batch
  const int kc = (EPI == 1) ? (bz & 1)  : 0;    // K-split chunk

  const int t    = threadIdx.x;
  const int lane = t & 63;
  const int wid  = t >> 6;
  const int wr   = wid >> 1, wc = wid & 1;      // 2x2 waves; wave C = 64x64
  const int fr   = lane & 15, fq = lane >> 4;

  // staging: thread t stages 16B at rows (t>>2) and (t>>2)+64, col (t&3)*8
  const int arow = t >> 2;
  const int acol = (t & 3) * 8;
  const ushort* Ag = A  + aStride * eb + (size_t)kc * kChunk
                        + (size_t)(by * 128 + arow) * lda + acol;
  const ushort* Bg = Bt + bStride * eb + (size_t)kc * kChunk
                        + (size_t)(bx * 128 + arow) * ldb + acol;

  f32x4 acc[4][4];
#pragma unroll
  for (int m = 0; m < 4; ++m)
#pragma unroll
    for (int n = 0; n < 4; ++n) acc[m][n] = (f32x4){0.f, 0.f, 0.f, 0.f};

  const ushort* aBase = &As[(wr * 64 + fr) * 32 + fq * 8];
  const ushort* bBase = &Bs[(wc * 64 + fr) * 32 + fq * 8];

  for (int k0 = 0; k0 < K; k0 += 32) {
    gload16(Ag,                     As + t * 8);
    gload16(Ag + (size_t)64 * lda,  As + t * 8 + 2048);
    gload16(Bg,                     Bs + t * 8);
    gload16(Bg + (size_t)64 * ldb,  Bs + t * 8 + 2048);
    __syncthreads();

    bf16x8 af[4], bfr[4];
#pragma unroll
    for (int m = 0; m < 4; ++m) af[m]  = *(const bf16x8*)(aBase + m * 16 * 32);
#pragma unroll
    for (int n = 0; n < 4; ++n) bfr[n] = *(const bf16x8*)(bBase + n * 16 * 32);
#pragma unroll
    for (int m = 0; m < 4; ++m)
#pragma unroll
      for (int n = 0; n < 4; ++n)
        acc[m][n] = __builtin_amdgcn_mfma_f32_16x16x32_bf16(af[m], bfr[n], acc[m][n], 0, 0, 0);
    __syncthreads();
    Ag += 32; Bg += 32;
  }

  // epilogue: col = gcol0 + n*16, row = grow0 + m*16 + j   [m89 mapping]
  const int grow0 = by * 128 + wr * 64 + fq * 4;
  const int gcol0 = bx * 128 + wc * 64 + fr;

  if (EPI == 0) {
    ushort* oo = (ushort*)outp + oStride * eb;
    const float* bb = bias + (size_t)biasStride * eb;
#pragma unroll
    for (int n = 0; n < 4; ++n) {
      const int cc = gcol0 + n * 16;
      const float bv = bb[cc];
#pragma unroll
      for (int m = 0; m < 4; ++m)
#pragma unroll
        for (int j = 0; j < 4; ++j) {
          const int r = grow0 + m * 16 + j;
          const float v = acc[m][n][j] + bv;
          oo[(size_t)r * ldo + cc] = f2bf(v > 0.f ? v : 0.f);
        }
    }
  } else if (EPI == 1) {
    float* oo = (float*)outp;
    const float* bb = bias + (size_t)biasStride * eb;
    const int e = ebase + eb;
    const float bscale = (kc == 0) ? 1.f : 0.f;
#pragma unroll
    for (int n = 0; n < 4; ++n) {
      const int cc = gcol0 + n * 16;
      const float bv = bb[cc] * bscale;
#pragma unroll
      for (int m = 0; m < 4; ++m)
#pragma unroll
        for (int j = 0; j < 4; ++j) {
          const int r = grow0 + m * 16 + j;
          atomicAdd(&oo[(size_t)r * ldo + cc],
                    gates[(size_t)r * 16 + e] * (acc[m][n][j] + bv));
        }
    }
  } else { // EPI 3: fused LoRA heads
    const bool second = (gcol0 >= ldo);
    const float* bp = second ? bias2 : bias;
    float* oo = (float*)outp + (second ? oStride : 0);
#pragma unroll
    for (int n = 0; n < 4; ++n) {
      const int cc = gcol0 + n * 16 - (second ? ldo : 0);
      const float bv = bp[cc];
#pragma unroll
      for (int m = 0; m < 4; ++m)
#pragma unroll
        for (int j = 0; j < 4; ++j) {
          const int r = grow0 + m * 16 + j;
          oo[(size_t)r * ldo + cc] = acc[m][n][j] + bv;
        }
    }
  }
}

// ---------------------------------------------------------------------------
// transpose + cvt: in (K,N) f32 -> out (N,K) bf16. 64x64 tiles, vectorized.
// ---------------------------------------------------------------------------
__global__ __launch_bounds__(256)
void transpose_cvt(const float* __restrict__ in, ushort* __restrict__ out,
                   int K, int N, size_t inStride, size_t outStride)
{
  __shared__ float tile[64][65];
  const float* I = in + inStride * blockIdx.z;
  ushort* O = out + outStride * blockIdx.z;
  const int n0 = blockIdx.x * 64, k0 = blockIdx.y * 64;
  const int t = threadIdx.x;
  const int r = t >> 4, cv = (t & 15) * 4;
#pragma unroll
  for (int pp = 0; pp < 4; ++pp) {
    const int kr = r + pp * 16;
    const float4 v = *(const float4*)&I[(size_t)(k0 + kr) * N + (n0 + cv)];
    tile[kr][cv] = v.x; tile[kr][cv + 1] = v.y; tile[kr][cv + 2] = v.z; tile[kr][cv + 3] = v.w;
  }
  __syncthreads();
#pragma unroll
  for (int pp = 0; pp < 4; ++pp) {
    const int nr = r + pp * 16;
    ushort4 o4;
    o4.x = f2bf(tile[cv + 0][nr]); o4.y = f2bf(tile[cv + 1][nr]);
    o4.z = f2bf(tile[cv + 2][nr]); o4.w = f2bf(tile[cv + 3][nr]);
    *(ushort4*)&O[(size_t)(n0 + nr) * K + (k0 + cv)] = o4;
  }
}

// x = concat(s, c) as bf16, row stride 1536. 8 elems/thread.
__global__ __launch_bounds__(256)
void build_x(const float* __restrict__ s, const float* __restrict__ c, ushort* __restrict__ x)
{
  const size_t i = (size_t)blockIdx.x * 256 + threadIdx.x;
  const size_t b = i / 192;
  const int col  = (int)(i % 192) * 8;
  const float* src = (col < 1024) ? (s + b * 1024 + col) : (c + b * 512 + (col - 1024));
  const float4 v0 = ((const float4*)src)[0];
  const float4 v1 = ((const float4*)src)[1];
  uint4 o;
  o.x = f2bf(v0.x) | ((uint32_t)f2bf(v0.y) << 16);
  o.y = f2bf(v0.z) | ((uint32_t)f2bf(v0.w) << 16);
  o.z = f2bf(v1.x) | ((uint32_t)f2bf(v1.y) << 16);
  o.w = f2bf(v1.z) | ((uint32_t)f2bf(v1.w) << 16);
  *(uint4*)(x + i * 8) = o;
}

__global__ __launch_bounds__(256)
void cvt_bf16(const float* __restrict__ in, ushort* __restrict__ out)
{
  const size_t i = (size_t)blockIdx.x * 256 + threadIdx.x;
  const float4 v0 = ((const float4*)(in + i * 8))[0];
  const float4 v1 = ((const float4*)(in + i * 8))[1];
  uint4 o;
  o.x = f2bf(v0.x) | ((uint32_t)f2bf(v0.y) << 16);
  o.y = f2bf(v0.z) | ((uint32_t)f2bf(v0.w) << 16);
  o.z = f2bf(v1.x) | ((uint32_t)f2bf(v1.y) << 16);
  o.w = f2bf(v1.z) | ((uint32_t)f2bf(v1.w) << 16);
  *(uint4*)(out + i * 8) = o;
}

// gating second layer + softmax: one wave per row.
__global__ __launch_bounds__(256)
void gating2_softmax(const ushort* __restrict__ hg, const float* __restrict__ Wg2,
                     const float* __restrict__ bg2, float* __restrict__ gates)
{
  const int row  = (int)((blockIdx.x * 256 + threadIdx.x) >> 6);
  const int lane = threadIdx.x & 63;
  float acc[16];
#pragma unroll
  for (int e = 0; e < 16; ++e) acc[e] = 0.f;
  const ushort* hrow = hg + (size_t)row * 2048;
#pragma unroll
  for (int it = 0; it < 4; ++it) {
    const int kb = it * 512 + lane * 8;
    const uint4 pk = *(const uint4*)(hrow + kb);
    float hv[8] = { bf2f(pk.x & 0xffffu), bf2f(pk.x >> 16),
                    bf2f(pk.y & 0xffffu), bf2f(pk.y >> 16),
                    bf2f(pk.z & 0xffffu), bf2f(pk.z >> 16),
                    bf2f(pk.w & 0xffffu), bf2f(pk.w >> 16) };
#pragma unroll
    for (int j = 0; j < 8; ++j) {
      const float* wrow = Wg2 + (size_t)(kb + j) * 16;
#pragma unroll
      for (int e = 0; e < 16; ++e) acc[e] += hv[j] * wrow[e];
    }
  }
#pragma unroll
  for (int e = 0; e < 16; ++e) {
#pragma unroll
    for (int off = 32; off > 0; off >>= 1) acc[e] += __shfl_xor(acc[e], off);
    acc[e] += bg2[e];
  }
  float mx = acc[0];
#pragma unroll
  for (int e = 1; e < 16; ++e) mx = fmaxf(mx, acc[e]);
  float sum = 0.f;
#pragma unroll
  for (int e = 0; e < 16; ++e) { acc[e] = __expf(acc[e] - mx); sum += acc[e]; }
  const float inv = 1.f / sum;
  if (lane == 0) {
#pragma unroll
    for (int e = 0; e < 16; ++e) gates[(size_t)row * 16 + e] = acc[e] * inv;
  }
}

// ---------------------------------------------------------------------------
extern "C" void kernel_launch(void* const* d_in, const int* in_sizes, int n_in,
                              void* d_out, int out_size, void* d_ws, size_t ws_size,
                              hipStream_t stream)
{
  (void)in_sizes; (void)n_in; (void)out_size;
  const float* s   = (const float*)d_in[0];
  const float* c   = (const float*)d_in[1];
  const float* Wg1 = (const float*)d_in[2];
  const float* bg1 = (const float*)d_in[3];
  const float* Wg2 = (const float*)d_in[4];
  const float* bg2 = (const float*)d_in[5];
  const float* We1 = (const float*)d_in[6];
  const float* be1 = (const float*)d_in[7];
  const float* We2 = (const float*)d_in[8];
  const float* be2 = (const float*)d_in[9];
  const float* WA  = (const float*)d_in[10];
  const float* bA  = (const float*)d_in[11];
  const float* WB  = (const float*)d_in[12];
  const float* bB  = (const float*)d_in[13];
  float* out = (float*)d_out;

  char* ws = (char*)d_ws;
  size_t off = 0;
  auto alloc = [&](size_t bytes) {
    void* p = ws + off; off += (bytes + 255) & ~(size_t)255; return p;
  };
  ushort* x     = (ushort*)alloc((size_t)4096 * 1536 * 2);      // 12.6 MB
  ushort* We1T  = (ushort*)alloc((size_t)16 * 2048 * 1536 * 2); // 100.7 MB
  ushort* We2T  = (ushort*)alloc((size_t)16 * 512 * 2048 * 2);  // 33.6 MB
  ushort* WABT  = (ushort*)alloc((size_t)32768 * 512 * 2);      // 33.6 MB
  float*  gates = (float*)alloc((size_t)4096 * 16 * 4);
  float*  z     = (float*)alloc((size_t)4096 * 512 * 4);        //  8.4 MB
  ushort* zb    = (ushort*)alloc((size_t)4096 * 512 * 2);       //  4.2 MB

  const size_t BH = (size_t)4096 * 2048 * 2; // 16.8 MB per expert h
  size_t rem = (ws_size > off) ? ws_size - off : 0;
  int GS = 2;
  if (rem >= 8 * BH) GS = 8;
  else if (rem >= 4 * BH) GS = 4;
  ushort* h = (ushort*)alloc((size_t)GS * BH);
  // aliases inside h (dead before h is first written):
  ushort* Wg1T = h;                                             // 4.2 MB
  ushort* hg   = (ushort*)((char*)h + (size_t)2048 * 1024 * 2); // 16.8 MB

  const size_t S_We1 = (size_t)2048 * 1536;
  const size_t S_We2 = (size_t)512 * 2048;
  const size_t S_h   = (size_t)4096 * 2048;

  build_x<<<3072, 256, 0, stream>>>(s, c, x);
  transpose_cvt<<<dim3(32, 16, 1),  256, 0, stream>>>(Wg1, Wg1T, 1024, 2048, 0, 0);
  transpose_cvt<<<dim3(32, 24, 16), 256, 0, stream>>>(We1, We1T, 1536, 2048, S_We1, S_We1);
  transpose_cvt<<<dim3(8, 32, 16),  256, 0, stream>>>(We2, We2T, 2048, 512, S_We2, S_We2);
  transpose_cvt<<<dim3(256, 8, 1),  256, 0, stream>>>(WA, WABT, 512, 16384, 0, 0);
  transpose_cvt<<<dim3(256, 8, 1),  256, 0, stream>>>(WB, WABT + (size_t)16384 * 512, 512, 16384, 0, 0);

  // gating: hg = relu(s @ Wg1 + bg1), then gates = softmax(hg @ Wg2 + bg2)
  gemm_bt<0, 0><<<dim3(16, 32, 1), 256, 0, stream>>>(x, Wg1T, bg1, nullptr, hg,
      1024, 1536, 1024, 2048, 0, 0, 0, 0, nullptr, 0, 0);
  gating2_softmax<<<1024, 256, 0, stream>>>(hg, Wg2, bg2, gates);

  hipMemsetAsync(z, 0, (size_t)4096 * 512 * 4, stream);

  for (int g = 0; g < 16; g += GS) {
    // h[e] = relu(x @ We1[e]^T + be1[e]); XCD chunk == one expert
    gemm_bt<0, 0><<<dim3(16, 32, GS), 256, 0, stream>>>(x, We1T + (size_t)g * S_We1,
        be1 + (size_t)g * 2048, nullptr, h,
        1536, 1536, 1536, 2048, 0, S_We1, 2048, S_h, nullptr, 0, 0);
    // z += gates[:,e] * (h[e] @ We2[e]^T + be2[e]); K-split x2 (bz = e*2+kc)
    gemm_bt<1, 0><<<dim3(4, 32, GS * 2), 256, 0, stream>>>(h, We2T + (size_t)g * S_We2,
        be2 + (size_t)g * 512, nullptr, z,
        1024, 2048, 2048, 512, S_h, S_We2, 512, 0, gates, g, 1024);
  }

  cvt_bf16<<<1024, 256, 0, stream>>>(z, zb);

  // fused LoRA heads: C = zb @ [WA; WB]^T; COL=1 -> XCD chunk = 4MB B slice
  gemm_bt<3, 1><<<dim3(256, 32, 1), 256, 0, stream>>>(zb, WABT, bA, bB, out,
      512, 512, 512, 16384, 0, 0, 0, (size_t)4096 * 16384, nullptr, 0, 0);
}

// Round 6
// 1446.418 us; speedup vs baseline: 1.3021x; 1.2220x over previous
//
#include <hip/hip_runtime.h>
#include <stdint.h>

typedef __attribute__((ext_vector_type(4))) float f32x4;
typedef __attribute__((ext_vector_type(8))) __bf16 bf16x8;

__device__ __forceinline__ ushort f2bf(float f) {
  union { float f; uint32_t u; } v; v.f = f;
  uint32_t r = v.u + 0x7fffu + ((v.u >> 16) & 1u);
  return (ushort)(r >> 16);
}
__device__ __forceinline__ float bf2f(uint32_t h) {
  union { uint32_t u; float f; } v; v.u = h << 16;
  return v.f;
}

// async global->LDS, 16B/lane; LDS dest is wave-uniform base + lane*16.
__device__ __forceinline__ void gload16(const void* g, const void* l) {
  __builtin_amdgcn_global_load_lds(
      (const __attribute__((address_space(1))) void*)(uintptr_t)g,
      (__attribute__((address_space(3))) void*)(uint32_t)(uintptr_t)l,
      16, 0, 0);
}

// ---------------------------------------------------------------------------
// GEMM: C(M,N) = A(M,K) * B^T(N,K), batched over blockIdx.z. Round-2 core
// (proven 1482us anchor): coalesced staging, 2-barrier K-loop, no remaps.
// COL=0: bx=blockIdx.x (N fastest; A-panel reuse)  -> for expert-2, gating
// COL=1: by=blockIdx.x (M fastest; B-panel reuse)  -> for expert-1, LoRA
//        (dispatch-order-robust: consecutive LINEAR ids share the B panel)
// EPI 0: out bf16 = relu(acc + bias[n]); out += oStride*eb
// EPI 1: z_part store: out[oStride*(ebase+eb) + r*ldo+c]
//                      = gates[r*16+ebase+eb] * (acc + bias[c])   (no atomics)
// EPI 3: fused LoRA: cols < ldo -> out+bias, else out+oStride+bias2
// ---------------------------------------------------------------------------
template<int EPI, int COL>
__global__ __launch_bounds__(256)
void gemm_bt(const ushort* __restrict__ A, const ushort* __restrict__ Bt,
             const float* __restrict__ bias, const float* __restrict__ bias2,
             void* __restrict__ outp,
             int K, int lda, int ldb, int ldo,
             size_t aStride, size_t bStride, int biasStride, size_t oStride,
             const float* __restrict__ gates, int ebase)
{
  __shared__ __attribute__((aligned(16))) ushort As[128 * 32];
  __shared__ __attribute__((aligned(16))) ushort Bs[128 * 32];

  const int bx = COL ? blockIdx.y : blockIdx.x;
  const int by = COL ? blockIdx.x : blockIdx.y;
  const int eb = blockIdx.z;

  const int t    = threadIdx.x;
  const int lane = t & 63;
  const int wid  = t >> 6;
  const int wr   = wid >> 1, wc = wid & 1;      // 2x2 waves; wave C = 64x64
  const int fr   = lane & 15, fq = lane >> 4;

  // staging: thread t stages 16B at rows (t>>2) and (t>>2)+64, col (t&3)*8
  const int arow = t >> 2;
  const int acol = (t & 3) * 8;
  const ushort* Ag = A  + aStride * eb + (size_t)(by * 128 + arow) * lda + acol;
  const ushort* Bg = Bt + bStride * eb + (size_t)(bx * 128 + arow) * ldb + acol;

  f32x4 acc[4][4];
#pragma unroll
  for (int m = 0; m < 4; ++m)
#pragma unroll
    for (int n = 0; n < 4; ++n) acc[m][n] = (f32x4){0.f, 0.f, 0.f, 0.f};

  const ushort* aBase = &As[(wr * 64 + fr) * 32 + fq * 8];
  const ushort* bBase = &Bs[(wc * 64 + fr) * 32 + fq * 8];

  for (int k0 = 0; k0 < K; k0 += 32) {
    gload16(Ag,                     As + t * 8);
    gload16(Ag + (size_t)64 * lda,  As + t * 8 + 2048);
    gload16(Bg,                     Bs + t * 8);
    gload16(Bg + (size_t)64 * ldb,  Bs + t * 8 + 2048);
    __syncthreads();

    bf16x8 af[4], bfr[4];
#pragma unroll
    for (int m = 0; m < 4; ++m) af[m]  = *(const bf16x8*)(aBase + m * 16 * 32);
#pragma unroll
    for (int n = 0; n < 4; ++n) bfr[n] = *(const bf16x8*)(bBase + n * 16 * 32);
#pragma unroll
    for (int m = 0; m < 4; ++m)
#pragma unroll
      for (int n = 0; n < 4; ++n)
        acc[m][n] = __builtin_amdgcn_mfma_f32_16x16x32_bf16(af[m], bfr[n], acc[m][n], 0, 0, 0);
    __syncthreads();
    Ag += 32; Bg += 32;
  }

  // epilogue: col = gcol0 + n*16, row = grow0 + m*16 + j   [m89 mapping]
  const int grow0 = by * 128 + wr * 64 + fq * 4;
  const int gcol0 = bx * 128 + wc * 64 + fr;

  if (EPI == 0) {
    ushort* oo = (ushort*)outp + oStride * eb;
    const float* bb = bias + (size_t)biasStride * eb;
#pragma unroll
    for (int n = 0; n < 4; ++n) {
      const int cc = gcol0 + n * 16;
      const float bv = bb[cc];
#pragma unroll
      for (int m = 0; m < 4; ++m)
#pragma unroll
        for (int j = 0; j < 4; ++j) {
          const int r = grow0 + m * 16 + j;
          const float v = acc[m][n][j] + bv;
          oo[(size_t)r * ldo + cc] = f2bf(v > 0.f ? v : 0.f);
        }
    }
  } else if (EPI == 1) {
    const int e = ebase + eb;
    float* oo = (float*)outp + oStride * e;
    const float* bb = bias + (size_t)biasStride * eb;
#pragma unroll
    for (int n = 0; n < 4; ++n) {
      const int cc = gcol0 + n * 16;
      const float bv = bb[cc];
#pragma unroll
      for (int m = 0; m < 4; ++m)
#pragma unroll
        for (int j = 0; j < 4; ++j) {
          const int r = grow0 + m * 16 + j;
          oo[(size_t)r * ldo + cc] =
              gates[(size_t)r * 16 + e] * (acc[m][n][j] + bv);
        }
    }
  } else { // EPI 3: fused LoRA heads
    const bool second = (gcol0 >= ldo);
    const float* bp = second ? bias2 : bias;
    float* oo = (float*)outp + (second ? oStride : 0);
#pragma unroll
    for (int n = 0; n < 4; ++n) {
      const int cc = gcol0 + n * 16 - (second ? ldo : 0);
      const float bv = bp[cc];
#pragma unroll
      for (int m = 0; m < 4; ++m)
#pragma unroll
        for (int j = 0; j < 4; ++j) {
          const int r = grow0 + m * 16 + j;
          oo[(size_t)r * ldo + cc] = acc[m][n][j] + bv;
        }
    }
  }
}

// ---------------------------------------------------------------------------
// transpose + cvt: in (K,N) f32 -> out (N,K) bf16. 64x64 tiles, vectorized.
// ---------------------------------------------------------------------------
__global__ __launch_bounds__(256)
void transpose_cvt(const float* __restrict__ in, ushort* __restrict__ out,
                   int K, int N, size_t inStride, size_t outStride)
{
  __shared__ float tile[64][65];
  const float* I = in + inStride * blockIdx.z;
  ushort* O = out + outStride * blockIdx.z;
  const int n0 = blockIdx.x * 64, k0 = blockIdx.y * 64;
  const int t = threadIdx.x;
  const int r = t >> 4, cv = (t & 15) * 4;
#pragma unroll
  for (int pp = 0; pp < 4; ++pp) {
    const int kr = r + pp * 16;
    const float4 v = *(const float4*)&I[(size_t)(k0 + kr) * N + (n0 + cv)];
    tile[kr][cv] = v.x; tile[kr][cv + 1] = v.y; tile[kr][cv + 2] = v.z; tile[kr][cv + 3] = v.w;
  }
  __syncthreads();
#pragma unroll
  for (int pp = 0; pp < 4; ++pp) {
    const int nr = r + pp * 16;
    ushort4 o4;
    o4.x = f2bf(tile[cv + 0][nr]); o4.y = f2bf(tile[cv + 1][nr]);
    o4.z = f2bf(tile[cv + 2][nr]); o4.w = f2bf(tile[cv + 3][nr]);
    *(ushort4*)&O[(size_t)(n0 + nr) * K + (k0 + cv)] = o4;
  }
}

// x = concat(s, c) as bf16, row stride 1536. 8 elems/thread.
__global__ __launch_bounds__(256)
void build_x(const float* __restrict__ s, const float* __restrict__ c, ushort* __restrict__ x)
{
  const size_t i = (size_t)blockIdx.x * 256 + threadIdx.x;
  const size_t b = i / 192;
  const int col  = (int)(i % 192) * 8;
  const float* src = (col < 1024) ? (s + b * 1024 + col) : (c + b * 512 + (col - 1024));
  const float4 v0 = ((const float4*)src)[0];
  const float4 v1 = ((const float4*)src)[1];
  uint4 o;
  o.x = f2bf(v0.x) | ((uint32_t)f2bf(v0.y) << 16);
  o.y = f2bf(v0.z) | ((uint32_t)f2bf(v0.w) << 16);
  o.z = f2bf(v1.x) | ((uint32_t)f2bf(v1.y) << 16);
  o.w = f2bf(v1.z) | ((uint32_t)f2bf(v1.w) << 16);
  *(uint4*)(x + i * 8) = o;
}

// zb = bf16( sum over 16 expert partials of z_part ), 4 floats/thread
__global__ __launch_bounds__(256)
void reduce_z(const float* __restrict__ zp, ushort* __restrict__ zb)
{
  const size_t i = ((size_t)blockIdx.x * 256 + threadIdx.x) * 4;
  const size_t S = (size_t)4096 * 512;
  float4 sv = {0.f, 0.f, 0.f, 0.f};
#pragma unroll
  for (int e = 0; e < 16; ++e) {
    const float4 v = *(const float4*)(zp + (size_t)e * S + i);
    sv.x += v.x; sv.y += v.y; sv.z += v.z; sv.w += v.w;
  }
  ushort4 o4;
  o4.x = f2bf(sv.x); o4.y = f2bf(sv.y); o4.z = f2bf(sv.z); o4.w = f2bf(sv.w);
  *(ushort4*)(zb + i) = o4;
}

// gating second layer + softmax: one wave per row.
__global__ __launch_bounds__(256)
void gating2_softmax(const ushort* __restrict__ hg, const float* __restrict__ Wg2,
                     const float* __restrict__ bg2, float* __restrict__ gates)
{
  const int row  = (int)((blockIdx.x * 256 + threadIdx.x) >> 6);
  const int lane = threadIdx.x & 63;
  float acc[16];
#pragma unroll
  for (int e = 0; e < 16; ++e) acc[e] = 0.f;
  const ushort* hrow = hg + (size_t)row * 2048;
#pragma unroll
  for (int it = 0; it < 4; ++it) {
    const int kb = it * 512 + lane * 8;
    const uint4 pk = *(const uint4*)(hrow + kb);
    float hv[8] = { bf2f(pk.x & 0xffffu), bf2f(pk.x >> 16),
                    bf2f(pk.y & 0xffffu), bf2f(pk.y >> 16),
                    bf2f(pk.z & 0xffffu), bf2f(pk.z >> 16),
                    bf2f(pk.w & 0xffffu), bf2f(pk.w >> 16) };
#pragma unroll
    for (int j = 0; j < 8; ++j) {
      const float* wrow = Wg2 + (size_t)(kb + j) * 16;
#pragma unroll
      for (int e = 0; e < 16; ++e) acc[e] += hv[j] * wrow[e];
    }
  }
#pragma unroll
  for (int e = 0; e < 16; ++e) {
#pragma unroll
    for (int off = 32; off > 0; off >>= 1) acc[e] += __shfl_xor(acc[e], off);
    acc[e] += bg2[e];
  }
  float mx = acc[0];
#pragma unroll
  for (int e = 1; e < 16; ++e) mx = fmaxf(mx, acc[e]);
  float sum = 0.f;
#pragma unroll
  for (int e = 0; e < 16; ++e) { acc[e] = __expf(acc[e] - mx); sum += acc[e]; }
  const float inv = 1.f / sum;
  if (lane == 0) {
#pragma unroll
    for (int e = 0; e < 16; ++e) gates[(size_t)row * 16 + e] = acc[e] * inv;
  }
}

// ---------------------------------------------------------------------------
extern "C" void kernel_launch(void* const* d_in, const int* in_sizes, int n_in,
                              void* d_out, int out_size, void* d_ws, size_t ws_size,
                              hipStream_t stream)
{
  (void)in_sizes; (void)n_in; (void)out_size;
  const float* s   = (const float*)d_in[0];
  const float* c   = (const float*)d_in[1];
  const float* Wg1 = (const float*)d_in[2];
  const float* bg1 = (const float*)d_in[3];
  const float* Wg2 = (const float*)d_in[4];
  const float* bg2 = (const float*)d_in[5];
  const float* We1 = (const float*)d_in[6];
  const float* be1 = (const float*)d_in[7];
  const float* We2 = (const float*)d_in[8];
  const float* be2 = (const float*)d_in[9];
  const float* WA  = (const float*)d_in[10];
  const float* bA  = (const float*)d_in[11];
  const float* WB  = (const float*)d_in[12];
  const float* bB  = (const float*)d_in[13];
  float* out = (float*)d_out;

  char* ws = (char*)d_ws;
  size_t off = 0;
  auto alloc = [&](size_t bytes) {
    void* p = ws + off; off += (bytes + 255) & ~(size_t)255; return p;
  };
  ushort* x     = (ushort*)alloc((size_t)4096 * 1536 * 2);      // 12.6 MB
  ushort* We1T  = (ushort*)alloc((size_t)16 * 2048 * 1536 * 2); // 100.7 MB
  ushort* We2T  = (ushort*)alloc((size_t)16 * 512 * 2048 * 2);  // 33.6 MB
  ushort* WABT  = (ushort*)alloc((size_t)32768 * 512 * 2);      // 33.6 MB
  float*  gates = (float*)alloc((size_t)4096 * 16 * 4);
  float*  zp    = (float*)alloc((size_t)16 * 4096 * 512 * 4);   // 134.2 MB
  ushort* zb    = (ushort*)alloc((size_t)4096 * 512 * 2);       //  4.2 MB

  const size_t BH = (size_t)4096 * 2048 * 2; // 16.8 MB per expert h
  size_t rem = (ws_size > off) ? ws_size - off : 0;
  int GS = 2;
  if (rem >= 16 * BH) GS = 16;
  else if (rem >= 8 * BH) GS = 8;
  else if (rem >= 4 * BH) GS = 4;
  ushort* h = (ushort*)alloc((size_t)GS * BH);
  // aliases inside h (dead before h is first written):
  ushort* Wg1T = h;                                             // 4.2 MB
  ushort* hg   = (ushort*)((char*)h + (size_t)2048 * 1024 * 2); // 16.8 MB

  const size_t S_We1 = (size_t)2048 * 1536;
  const size_t S_We2 = (size_t)512 * 2048;
  const size_t S_h   = (size_t)4096 * 2048;
  const size_t S_z   = (size_t)4096 * 512;

  build_x<<<3072, 256, 0, stream>>>(s, c, x);
  transpose_cvt<<<dim3(32, 16, 1),  256, 0, stream>>>(Wg1, Wg1T, 1024, 2048, 0, 0);
  transpose_cvt<<<dim3(32, 24, 16), 256, 0, stream>>>(We1, We1T, 1536, 2048, S_We1, S_We1);
  transpose_cvt<<<dim3(8, 32, 16),  256, 0, stream>>>(We2, We2T, 2048, 512, S_We2, S_We2);
  transpose_cvt<<<dim3(256, 8, 1),  256, 0, stream>>>(WA, WABT, 512, 16384, 0, 0);
  transpose_cvt<<<dim3(256, 8, 1),  256, 0, stream>>>(WB, WABT + (size_t)16384 * 512, 512, 16384, 0, 0);

  // gating: hg = relu(s @ Wg1 + bg1), then gates = softmax(hg @ Wg2 + bg2)
  gemm_bt<0, 0><<<dim3(16, 32, 1), 256, 0, stream>>>(x, Wg1T, bg1, nullptr, hg,
      1024, 1536, 1024, 2048, 0, 0, 0, 0, nullptr, 0);
  gating2_softmax<<<1024, 256, 0, stream>>>(hg, Wg2, bg2, gates);

  for (int g = 0; g < 16; g += GS) {
    // h[e] = relu(x @ We1[e]^T + be1[e]); COL=1: M-major -> B-panel L2 reuse
    gemm_bt<0, 1><<<dim3(32, 16, GS), 256, 0, stream>>>(x, We1T + (size_t)g * S_We1,
        be1 + (size_t)g * 2048, nullptr, h,
        1536, 1536, 1536, 2048, 0, S_We1, 2048, S_h, nullptr, 0);
    // z_part[e] = gates[:,e] * (h[e] @ We2[e]^T + be2[e])  (plain stores)
    gemm_bt<1, 0><<<dim3(4, 32, GS), 256, 0, stream>>>(h, We2T + (size_t)g * S_We2,
        be2 + (size_t)g * 512, nullptr, zp,
        2048, 2048, 2048, 512, S_h, S_We2, 512, S_z, gates, g);
  }

  // zb = bf16( sum_e z_part[e] )
  reduce_z<<<2048, 256, 0, stream>>>(zp, zb);

  // fused LoRA heads: C = zb @ [WA; WB]^T; COL=1 M-major (B-panel reuse)
  gemm_bt<3, 1><<<dim3(32, 256, 1), 256, 0, stream>>>(zb, WABT, bA, bB, out,
      512, 512, 512, 16384, 0, 0, 0, (size_t)4096 * 16384, nullptr, 0);
}

// Round 7
// 1158.225 us; speedup vs baseline: 1.6261x; 1.2488x over previous
//
#include <hip/hip_runtime.h>
#include <stdint.h>

typedef __attribute__((ext_vector_type(4))) float f32x4;
typedef __attribute__((ext_vector_type(8))) __bf16 bf16x8;

__device__ __forceinline__ ushort f2bf(float f) {
  union { float f; uint32_t u; } v; v.f = f;
  uint32_t r = v.u + 0x7fffu + ((v.u >> 16) & 1u);
  return (ushort)(r >> 16);
}
__device__ __forceinline__ float bf2f(uint32_t h) {
  union { uint32_t u; float f; } v; v.u = h << 16;
  return v.f;
}

// async global->LDS, 16B/lane; LDS dest is wave-uniform base + lane*16.
__device__ __forceinline__ void gload16(const void* g, const void* l) {
  __builtin_amdgcn_global_load_lds(
      (const __attribute__((address_space(1))) void*)(uintptr_t)g,
      (__attribute__((address_space(3))) void*)(uint32_t)(uintptr_t)l,
      16, 0, 0);
}

// ---------------------------------------------------------------------------
// Pipelined GEMM: C(M,N) = A(M,K) * B^T(N,K), batched over blockIdx.z.
// 256x256 tile, BK=32, 512 threads (8 waves 2Mx4N), ring-3 LDS slots (96KB).
// Two phases per K-tile; each phase: vmcnt(counted) -> barrier -> issue 2
// global_load_lds -> ds_read frags -> setprio(1) 16 MFMA setprio(0).
// Staging order per tile: [Ah0'(mh0 rows), B0, B1, Ah1'(mh1 rows)], 1 gload
// each; tile T+2 staged during iter T (slot freed at iter T's phase-1 barrier).
// Steady-state waits: phi1 vmcnt(5), phi2 vmcnt(6) (3 half-tiles in flight).
// LDS swizzle (both-sides, rule 21): chunk' = chunk ^ ((row>>1)&3) applied on
// the global SOURCE within each row's 64B segment (coalescing preserved) and
// on the ds_read chunk select -> 2 words/bank (free) instead of 8-way.
//   A slot: [2 mh][128 r][4 chunk][16B]; mh-block r -> global row
//   by*256 + (r>>6)*128 + mh*64 + (r&63).  B slot: [256 r][4 chunk][16B].
// EPI 0: out bf16 = relu(acc + bias[n]); out += oStride*eb
// EPI 1: out[oStride*(ebase+eb) + r*ldo+c] = gates[r*16+e]*(acc+bias[c])
// EPI 3: fused LoRA: cols < ldo -> out+bias, else out+oStride+bias2
// ---------------------------------------------------------------------------
template<int EPI, int COL>
__global__ __launch_bounds__(512, 1)
void gemm256p(const ushort* __restrict__ A, const ushort* __restrict__ Bt,
              const float* __restrict__ bias, const float* __restrict__ bias2,
              void* __restrict__ outp,
              int K, int lda, int ldb, int ldo,
              size_t aStride, size_t bStride, int biasStride, size_t oStride,
              const float* __restrict__ gates, int ebase)
{
  __shared__ __attribute__((aligned(16))) char smem[3 * 32768];

  const int bx = COL ? blockIdx.y : blockIdx.x;
  const int by = COL ? blockIdx.x : blockIdx.y;
  const int eb = blockIdx.z;

  const int t    = threadIdx.x;
  const int lane = t & 63;
  const int wid  = t >> 6;
  const int wr   = wid >> 2, wc = wid & 3;   // 2x4 waves; wave C = 128x64
  const int fr   = lane & 15, fq = lane >> 4;

  // --- staging sources (chunk-permuted within each row's 64B segment) ---
  const int r  = t >> 2;                     // 0..127
  const int jc = (t & 3) ^ ((t >> 3) & 3);   // swizzled 16B-chunk index
  const ushort* Ae = A  + aStride * eb;
  const ushort* Be = Bt + bStride * eb;
  const ushort* sA0 = Ae + (size_t)(by * 256 + (r >> 6) * 128 +   0 + (r & 63)) * lda + jc * 8;
  const ushort* sA1 = Ae + (size_t)(by * 256 + (r >> 6) * 128 +  64 + (r & 63)) * lda + jc * 8;
  const ushort* sB0 = Be + (size_t)(bx * 256 +   0 + r) * ldb + jc * 8;
  const ushort* sB1 = Be + (size_t)(bx * 256 + 128 + r) * ldb + jc * 8;
  const int dT = t * 16;

  // --- ds_read bases (swizzled chunk select; constant per lane) ---
  const int swz  = (fq ^ ((fr >> 1) & 3)) * 16;
  const int aOff = (wr * 64 + fr) * 64 + swz;          // + mh*8192 + m*1024
  const int bOff = 16384 + (wc * 64 + fr) * 64 + swz;  // + n*1024

  f32x4 acc[8][4];
#pragma unroll
  for (int m = 0; m < 8; ++m)
#pragma unroll
    for (int n = 0; n < 4; ++n) acc[m][n] = (f32x4){0.f, 0.f, 0.f, 0.f};

  const int NT = K >> 5;

  // prologue: tiles 0 and 1, consumption order [Ah0', B0, B1, Ah1']
#pragma unroll
  for (int kt = 0; kt < 2; ++kt) {
    char* d = smem + kt * 32768;
    gload16(sA0 + kt * 32, d + dT);
    gload16(sB0 + kt * 32, d + 16384 + dT);
    gload16(sB1 + kt * 32, d + 24576 + dT);
    gload16(sA1 + kt * 32, d + 8192 + dT);
  }

  int sc = 0;
  for (int T = 0; T < NT; ++T) {
    const char* base = smem + sc * 32768;
    const int ssi = (sc + 2 >= 3) ? sc - 1 : sc + 2;   // (T+2)%3
    char* d = smem + ssi * 32768;
    const bool pf = (T + 2 < NT);
    const int ko = (T + 2) * 32;

    // ---- phase 1 (mh=0) ----
    if (T < NT - 1) asm volatile("s_waitcnt vmcnt(5)" ::: "memory");
    else            asm volatile("s_waitcnt vmcnt(1)" ::: "memory");
    __builtin_amdgcn_s_barrier();
    if (pf) { gload16(sA0 + ko, d + dT); gload16(sB0 + ko, d + 16384 + dT); }

    bf16x8 af[4], bf[4];
#pragma unroll
    for (int m = 0; m < 4; ++m) af[m] = *(const bf16x8*)(base + aOff + m * 1024);
#pragma unroll
    for (int n = 0; n < 4; ++n) bf[n] = *(const bf16x8*)(base + bOff + n * 1024);
    __builtin_amdgcn_s_setprio(1);
#pragma unroll
    for (int m = 0; m < 4; ++m)
#pragma unroll
      for (int n = 0; n < 4; ++n)
        acc[m][n] = __builtin_amdgcn_mfma_f32_16x16x32_bf16(af[m], bf[n], acc[m][n], 0, 0, 0);
    __builtin_amdgcn_s_setprio(0);

    // ---- phase 2 (mh=1) ----
    if (T < NT - 2)       asm volatile("s_waitcnt vmcnt(6)" ::: "memory");
    else if (T == NT - 2) asm volatile("s_waitcnt vmcnt(4)" ::: "memory");
    else                  asm volatile("s_waitcnt vmcnt(0)" ::: "memory");
    __builtin_amdgcn_s_barrier();
    if (pf) { gload16(sB1 + ko, d + 24576 + dT); gload16(sA1 + ko, d + 8192 + dT); }

#pragma unroll
    for (int m = 0; m < 4; ++m) af[m] = *(const bf16x8*)(base + 8192 + aOff + m * 1024);
    __builtin_amdgcn_s_setprio(1);
#pragma unroll
    for (int m = 0; m < 4; ++m)
#pragma unroll
      for (int n = 0; n < 4; ++n)
        acc[4 + m][n] = __builtin_amdgcn_mfma_f32_16x16x32_bf16(af[m], bf[n], acc[4 + m][n], 0, 0, 0);
    __builtin_amdgcn_s_setprio(0);

    sc = (sc + 1 == 3) ? 0 : sc + 1;
  }

  // epilogue: row = by*256 + wr*128 + (m>>2)*64 + (m&3)*16 + fq*4 + j
  //           col = bx*256 + wc*64 + n*16 + fr          [r2-proven mapping]
  const int grow0 = by * 256 + wr * 128 + fq * 4;
  const int gcol0 = bx * 256 + wc * 64 + fr;

  if (EPI == 0) {
    ushort* oo = (ushort*)outp + oStride * eb;
    const float* bb = bias + (size_t)biasStride * eb;
#pragma unroll
    for (int n = 0; n < 4; ++n) {
      const int cc = gcol0 + n * 16;
      const float bv = bb[cc];
#pragma unroll
      for (int m = 0; m < 8; ++m) {
        const int rb = grow0 + (m >> 2) * 64 + (m & 3) * 16;
#pragma unroll
        for (int j = 0; j < 4; ++j) {
          const float v = acc[m][n][j] + bv;
          oo[(size_t)(rb + j) * ldo + cc] = f2bf(v > 0.f ? v : 0.f);
        }
      }
    }
  } else if (EPI == 1) {
    const int e = ebase + eb;
    float* oo = (float*)outp + oStride * e;
    const float* bb = bias + (size_t)biasStride * eb;
#pragma unroll
    for (int n = 0; n < 4; ++n) {
      const int cc = gcol0 + n * 16;
      const float bv = bb[cc];
#pragma unroll
      for (int m = 0; m < 8; ++m) {
        const int rb = grow0 + (m >> 2) * 64 + (m & 3) * 16;
#pragma unroll
        for (int j = 0; j < 4; ++j) {
          const int rr = rb + j;
          oo[(size_t)rr * ldo + cc] =
              gates[(size_t)rr * 16 + e] * (acc[m][n][j] + bv);
        }
      }
    }
  } else { // EPI 3: fused LoRA heads
    const bool second = (gcol0 >= ldo);
    const float* bp = second ? bias2 : bias;
    float* oo = (float*)outp + (second ? oStride : 0);
#pragma unroll
    for (int n = 0; n < 4; ++n) {
      const int cc = gcol0 + n * 16 - (second ? ldo : 0);
      const float bv = bp[cc];
#pragma unroll
      for (int m = 0; m < 8; ++m) {
        const int rb = grow0 + (m >> 2) * 64 + (m & 3) * 16;
#pragma unroll
        for (int j = 0; j < 4; ++j)
          oo[(size_t)(rb + j) * ldo + cc] = acc[m][n][j] + bv;
      }
    }
  }
}

// ---------------------------------------------------------------------------
// transpose + cvt: in (K,N) f32 -> out (N,K) bf16. 64x64 tiles, vectorized.
// ---------------------------------------------------------------------------
__global__ __launch_bounds__(256)
void transpose_cvt(const float* __restrict__ in, ushort* __restrict__ out,
                   int K, int N, size_t inStride, size_t outStride)
{
  __shared__ float tile[64][65];
  const float* I = in + inStride * blockIdx.z;
  ushort* O = out + outStride * blockIdx.z;
  const int n0 = blockIdx.x * 64, k0 = blockIdx.y * 64;
  const int t = threadIdx.x;
  const int r = t >> 4, cv = (t & 15) * 4;
#pragma unroll
  for (int pp = 0; pp < 4; ++pp) {
    const int kr = r + pp * 16;
    const float4 v = *(const float4*)&I[(size_t)(k0 + kr) * N + (n0 + cv)];
    tile[kr][cv] = v.x; tile[kr][cv + 1] = v.y; tile[kr][cv + 2] = v.z; tile[kr][cv + 3] = v.w;
  }
  __syncthreads();
#pragma unroll
  for (int pp = 0; pp < 4; ++pp) {
    const int nr = r + pp * 16;
    ushort4 o4;
    o4.x = f2bf(tile[cv + 0][nr]); o4.y = f2bf(tile[cv + 1][nr]);
    o4.z = f2bf(tile[cv + 2][nr]); o4.w = f2bf(tile[cv + 3][nr]);
    *(ushort4*)&O[(size_t)(n0 + nr) * K + (k0 + cv)] = o4;
  }
}

// x = concat(s, c) as bf16, row stride 1536. 8 elems/thread.
__global__ __launch_bounds__(256)
void build_x(const float* __restrict__ s, const float* __restrict__ c, ushort* __restrict__ x)
{
  const size_t i = (size_t)blockIdx.x * 256 + threadIdx.x;
  const size_t b = i / 192;
  const int col  = (int)(i % 192) * 8;
  const float* src = (col < 1024) ? (s + b * 1024 + col) : (c + b * 512 + (col - 1024));
  const float4 v0 = ((const float4*)src)[0];
  const float4 v1 = ((const float4*)src)[1];
  uint4 o;
  o.x = f2bf(v0.x) | ((uint32_t)f2bf(v0.y) << 16);
  o.y = f2bf(v0.z) | ((uint32_t)f2bf(v0.w) << 16);
  o.z = f2bf(v1.x) | ((uint32_t)f2bf(v1.y) << 16);
  o.w = f2bf(v1.z) | ((uint32_t)f2bf(v1.w) << 16);
  *(uint4*)(x + i * 8) = o;
}

// zb = bf16( sum over 16 expert partials of z_part ), 4 floats/thread
__global__ __launch_bounds__(256)
void reduce_z(const float* __restrict__ zp, ushort* __restrict__ zb)
{
  const size_t i = ((size_t)blockIdx.x * 256 + threadIdx.x) * 4;
  const size_t S = (size_t)4096 * 512;
  float4 sv = {0.f, 0.f, 0.f, 0.f};
#pragma unroll
  for (int e = 0; e < 16; ++e) {
    const float4 v = *(const float4*)(zp + (size_t)e * S + i);
    sv.x += v.x; sv.y += v.y; sv.z += v.z; sv.w += v.w;
  }
  ushort4 o4;
  o4.x = f2bf(sv.x); o4.y = f2bf(sv.y); o4.z = f2bf(sv.z); o4.w = f2bf(sv.w);
  *(ushort4*)(zb + i) = o4;
}

// gating second layer + softmax: one wave per row.
__global__ __launch_bounds__(256)
void gating2_softmax(const ushort* __restrict__ hg, const float* __restrict__ Wg2,
                     const float* __restrict__ bg2, float* __restrict__ gates)
{
  const int row  = (int)((blockIdx.x * 256 + threadIdx.x) >> 6);
  const int lane = threadIdx.x & 63;
  float acc[16];
#pragma unroll
  for (int e = 0; e < 16; ++e) acc[e] = 0.f;
  const ushort* hrow = hg + (size_t)row * 2048;
#pragma unroll
  for (int it = 0; it < 4; ++it) {
    const int kb = it * 512 + lane * 8;
    const uint4 pk = *(const uint4*)(hrow + kb);
    float hv[8] = { bf2f(pk.x & 0xffffu), bf2f(pk.x >> 16),
                    bf2f(pk.y & 0xffffu), bf2f(pk.y >> 16),
                    bf2f(pk.z & 0xffffu), bf2f(pk.z >> 16),
                    bf2f(pk.w & 0xffffu), bf2f(pk.w >> 16) };
#pragma unroll
    for (int j = 0; j < 8; ++j) {
      const float* wrow = Wg2 + (size_t)(kb + j) * 16;
#pragma unroll
      for (int e = 0; e < 16; ++e) acc[e] += hv[j] * wrow[e];
    }
  }
#pragma unroll
  for (int e = 0; e < 16; ++e) {
#pragma unroll
    for (int off = 32; off > 0; off >>= 1) acc[e] += __shfl_xor(acc[e], off);
    acc[e] += bg2[e];
  }
  float mx = acc[0];
#pragma unroll
  for (int e = 1; e < 16; ++e) mx = fmaxf(mx, acc[e]);
  float sum = 0.f;
#pragma unroll
  for (int e = 0; e < 16; ++e) { acc[e] = __expf(acc[e] - mx); sum += acc[e]; }
  const float inv = 1.f / sum;
  if (lane == 0) {
#pragma unroll
    for (int e = 0; e < 16; ++e) gates[(size_t)row * 16 + e] = acc[e] * inv;
  }
}

// ---------------------------------------------------------------------------
extern "C" void kernel_launch(void* const* d_in, const int* in_sizes, int n_in,
                              void* d_out, int out_size, void* d_ws, size_t ws_size,
                              hipStream_t stream)
{
  (void)in_sizes; (void)n_in; (void)out_size;
  const float* s   = (const float*)d_in[0];
  const float* c   = (const float*)d_in[1];
  const float* Wg1 = (const float*)d_in[2];
  const float* bg1 = (const float*)d_in[3];
  const float* Wg2 = (const float*)d_in[4];
  const float* bg2 = (const float*)d_in[5];
  const float* We1 = (const float*)d_in[6];
  const float* be1 = (const float*)d_in[7];
  const float* We2 = (const float*)d_in[8];
  const float* be2 = (const float*)d_in[9];
  const float* WA  = (const float*)d_in[10];
  const float* bA  = (const float*)d_in[11];
  const float* WB  = (const float*)d_in[12];
  const float* bB  = (const float*)d_in[13];
  float* out = (float*)d_out;

  char* ws = (char*)d_ws;
  size_t off = 0;
  auto alloc = [&](size_t bytes) {
    void* p = ws + off; off += (bytes + 255) & ~(size_t)255; return p;
  };
  ushort* x     = (ushort*)alloc((size_t)4096 * 1536 * 2);      // 12.6 MB
  ushort* We1T  = (ushort*)alloc((size_t)16 * 2048 * 1536 * 2); // 100.7 MB
  ushort* We2T  = (ushort*)alloc((size_t)16 * 512 * 2048 * 2);  // 33.6 MB
  ushort* WABT  = (ushort*)alloc((size_t)32768 * 512 * 2);      // 33.6 MB
  float*  gates = (float*)alloc((size_t)4096 * 16 * 4);
  float*  zp    = (float*)alloc((size_t)16 * 4096 * 512 * 4);   // 134.2 MB
  ushort* zb    = (ushort*)alloc((size_t)4096 * 512 * 2);       //  4.2 MB

  const size_t BH = (size_t)4096 * 2048 * 2; // 16.8 MB per expert h
  size_t rem = (ws_size > off) ? ws_size - off : 0;
  int GS = 2;
  if (rem >= 16 * BH) GS = 16;
  else if (rem >= 8 * BH) GS = 8;
  else if (rem >= 4 * BH) GS = 4;
  ushort* h = (ushort*)alloc((size_t)GS * BH);
  // aliases inside h (dead before h is first written):
  ushort* Wg1T = h;                                             // 4.2 MB
  ushort* hg   = (ushort*)((char*)h + (size_t)2048 * 1024 * 2); // 16.8 MB

  const size_t S_We1 = (size_t)2048 * 1536;
  const size_t S_We2 = (size_t)512 * 2048;
  const size_t S_h   = (size_t)4096 * 2048;
  const size_t S_z   = (size_t)4096 * 512;

  build_x<<<3072, 256, 0, stream>>>(s, c, x);
  transpose_cvt<<<dim3(32, 16, 1),  256, 0, stream>>>(Wg1, Wg1T, 1024, 2048, 0, 0);
  transpose_cvt<<<dim3(32, 24, 16), 256, 0, stream>>>(We1, We1T, 1536, 2048, S_We1, S_We1);
  transpose_cvt<<<dim3(8, 32, 16),  256, 0, stream>>>(We2, We2T, 2048, 512, S_We2, S_We2);
  transpose_cvt<<<dim3(256, 8, 1),  256, 0, stream>>>(WA, WABT, 512, 16384, 0, 0);
  transpose_cvt<<<dim3(256, 8, 1),  256, 0, stream>>>(WB, WABT + (size_t)16384 * 512, 512, 16384, 0, 0);

  // gating: hg = relu(s @ Wg1 + bg1), then gates = softmax(hg @ Wg2 + bg2)
  gemm256p<0, 1><<<dim3(16, 8, 1), 512, 0, stream>>>(x, Wg1T, bg1, nullptr, hg,
      1024, 1536, 1024, 2048, 0, 0, 0, 0, nullptr, 0);
  gating2_softmax<<<1024, 256, 0, stream>>>(hg, Wg2, bg2, gates);

  for (int g = 0; g < 16; g += GS) {
    // h[e] = relu(x @ We1[e]^T + be1[e]); M-fastest grid (B-panel reuse)
    gemm256p<0, 1><<<dim3(16, 8, GS), 512, 0, stream>>>(x, We1T + (size_t)g * S_We1,
        be1 + (size_t)g * 2048, nullptr, h,
        1536, 1536, 1536, 2048, 0, S_We1, 2048, S_h, nullptr, 0);
    // z_part[e] = gates[:,e] * (h[e] @ We2[e]^T + be2[e])  (plain stores)
    gemm256p<1, 0><<<dim3(2, 16, GS), 512, 0, stream>>>(h, We2T + (size_t)g * S_We2,
        be2 + (size_t)g * 512, nullptr, zp,
        2048, 2048, 2048, 512, S_h, S_We2, 512, S_z, gates, g);
  }

  // zb = bf16( sum_e z_part[e] )
  reduce_z<<<2048, 256, 0, stream>>>(zp, zb);

  // fused LoRA heads: C = zb @ [WA; WB]^T; M-fastest grid
  gemm256p<3, 1><<<dim3(16, 128, 1), 512, 0, stream>>>(zb, WABT, bA, bB, out,
      512, 512, 512, 16384, 0, 0, 0, (size_t)4096 * 16384, nullptr, 0);
}